// Round 20
// baseline (130.930 us; speedup 1.0000x reference)
//
#include <hip/hip_runtime.h>
#include <hip/hip_bf16.h>

#define DIM 64
#define BKN 64               // nodes per bucket
#define BKSH 6               // log2(BKN)
#define MAXBK 1600           // supports N <= 102400
#define PCHUNK 8192          // edges per place block (stage = 32 KB)
#define MAXPB 512            // max place blocks (E <= 4.19M)
#define CAP 2944             // gather LDS record capacity; mean ~2048, ~20 sigma

__device__ inline float fast_tanh(float x) {
    float e = __expf(2.0f * x);
    return 1.0f - 2.0f / (e + 1.0f);
}

__device__ inline float4 i8x4_unpack(uint q) {
    return make_float4((float)((int)(q << 24) >> 24),
                       (float)((int)(q << 16) >> 24),
                       (float)((int)(q <<  8) >> 24),
                       (float)((int)q >> 24));
}

// ---------- fused: place role (blocks [0,nplace)) + gates/quant role (rest) ----------
// seg table layout [blk][bk] (int2{start,len}): contiguous per-block writes.
__global__ __launch_bounds__(1024)
void fa_place_gates(const float* __restrict__ h,
                    const float* __restrict__ gate_W,
                    const float* __restrict__ dn,
                    float2* __restrict__ gdd,
                    float4* __restrict__ gss4,
                    unsigned char* __restrict__ hq,
                    const int* __restrict__ esrc, const int* __restrict__ edst,
                    int2* __restrict__ seglen,
                    int* __restrict__ pairs,
                    int E, int N, int nbk, int nplace) {
    __shared__ int stage[PCHUNK];                 // 32 KB staged records
    __shared__ int lh[2048];
    __shared__ int lex[2048];
    __shared__ int wtot[16];
    int tid = threadIdx.x;                        // 1024 threads
    if ((int)blockIdx.x < nplace) {
        int blk = blockIdx.x;
        int c0 = blk * PCHUNK;
        int c1 = min(E, c0 + PCHUNK);
        lh[tid] = 0; lh[tid + 1024] = 0;
        __syncthreads();
        // phase A: read edges once; stage record in LDS; histogram
        for (int i = c0 + tid; i < c1; i += 1024) {
            int t = edst[i];
            int s = esrc[i];
            stage[i - c0] = (s << BKSH) | (t & (BKN - 1));
            atomicAdd(&lh[t >> BKSH], 1);
        }
        __syncthreads();
        // phase B: wave-level exclusive scan over 2048 buckets (2 per thread)
        int lane = tid & 63, wv = tid >> 6;       // 16 waves
        int a0 = lh[2 * tid], a1 = lh[2 * tid + 1];
        int s = a0 + a1;
        int v = s;
        #pragma unroll
        for (int d = 1; d < 64; d <<= 1) {
            int t = __shfl_up(v, d, 64);
            if (lane >= d) v += t;
        }
        if (lane == 63) wtot[wv] = v;
        __syncthreads();
        int base = 0;
        #pragma unroll
        for (int k = 0; k < 16; ++k) base += (k < wv) ? wtot[k] : 0;
        int excl = v + base - s;
        lex[2 * tid] = excl;
        lex[2 * tid + 1] = excl + a0;
        __syncthreads();
        // segment table: contiguous per-block row [blk][bk]
        int2* row = seglen + (size_t)blk * MAXBK;
        for (int i = tid; i < nbk; i += 1024)
            row[i] = make_int2(c0 + lex[i], lh[i]);
        __syncthreads();
        // phase C: place staged records (edst re-read is L2-hot)
        for (int i = c0 + tid; i < c1; i += 1024) {
            int t = edst[i];
            int pos = c0 + atomicAdd(&lex[t >> BKSH], 1);
            pairs[pos] = stage[i - c0];
        }
    } else {
        // -------- gates + int8 quantization: 64 nodes/block, 4 nodes/wave --------
        int base_node = (blockIdx.x - nplace) * 64;
        int wv   = tid >> 6;
        int lane = tid & 63;
        int l16  = lane & 15;
        int node = base_node + (wv << 2) + (lane >> 4);
        if (node >= N) return;
        float4 x4 = ((const float4*)h)[(size_t)node * 16 + l16];
        float4 w0 = ((const float4*)gate_W)[l16];
        float4 w1 = ((const float4*)gate_W)[16 + l16];
        float a = x4.x * w0.x + x4.y * w0.y + x4.z * w0.z + x4.w * w0.w;
        float b = x4.x * w1.x + x4.y * w1.y + x4.z * w1.z + x4.w * w1.w;
        float m = fmaxf(fmaxf(fabsf(x4.x), fabsf(x4.y)),
                        fmaxf(fabsf(x4.z), fabsf(x4.w)));
        #pragma unroll
        for (int off = 1; off < 16; off <<= 1) {
            a += __shfl_xor(a, off, 16);
            b += __shfl_xor(b, off, 16);
            m = fmaxf(m, __shfl_xor(m, off, 16));
        }
        float inv = (m > 0.f) ? (127.0f / m) : 0.f;
        int q0 = __float2int_rn(x4.x * inv) & 0xff;
        int q1 = __float2int_rn(x4.y * inv) & 0xff;
        int q2 = __float2int_rn(x4.z * inv) & 0xff;
        int q3 = __float2int_rn(x4.w * inv) & 0xff;
        ((uint*)hq)[(size_t)node * 16 + l16] =
            (uint)q0 | ((uint)q1 << 8) | ((uint)q2 << 16) | ((uint)q3 << 24);
        if (l16 == 0) {
            float dv = dn[node];
            gdd[node]  = make_float2(a, dv);
            gss4[node] = make_float4(b, dv, m / 127.0f, 0.f);
        }
    }
}

// ---------- standalone gates (fallback path only) ----------
__global__ void fa_node_gates(const float* __restrict__ h,
                              const float* __restrict__ gate_W,
                              const float* __restrict__ dn,
                              float2* __restrict__ gdd,
                              float4* __restrict__ gss4,
                              int N) {
    int gid  = blockIdx.x * blockDim.x + threadIdx.x;
    int node = gid >> 6;
    int lane = threadIdx.x & 63;
    if (node >= N) return;
    float x = h[(size_t)node * DIM + lane];
    float a = x * gate_W[lane];
    float b = x * gate_W[DIM + lane];
    #pragma unroll
    for (int off = 32; off >= 1; off >>= 1) {
        a += __shfl_xor(a, off, 64);
        b += __shfl_xor(b, off, 64);
    }
    if (lane == 0) {
        float dv = dn[node];
        gdd[node]  = make_float2(a, dv);
        gss4[node] = make_float4(b, dv, 0.f, 0.f);
    }
}

// ---------- gather: persistent blocks, dynamic bucket queue ----------
__global__ __launch_bounds__(512, 4)
void fa_gather13(const unsigned char* __restrict__ hq,
                 const float2* __restrict__ gdd, const float4* __restrict__ gss4,
                 const float* __restrict__ gate_b,
                 const int2* __restrict__ seglen,
                 const int* __restrict__ pairs,
                 int* __restrict__ wq,
                 float* __restrict__ z, int N, int nbk, int nplace) {
    __shared__ int  stg[CAP];                    // 11.5 KB raw records
    __shared__ int2 buf2[CAP];                   // 23 KB; first 2KB doubles as sstart scratch
    __shared__ int  sc[512];                     // segment-length inclusive scan
    __shared__ int  wtot[8];
    __shared__ float2 gdl[BKN];
    __shared__ int hist[BKN];
    __shared__ int cur[BKN];
    __shared__ int offl[BKN + 1];
    __shared__ int sbk;
    int tid = threadIdx.x;                       // 512 threads = 8 waves
    int wid  = tid >> 6;
    int lane = tid & 63;
    int qid = lane >> 4;
    int l16 = lane & 15;
    float gb = gate_b[0];
    int q8  = nbk >> 3, r8 = nbk & 7;
    for (;;) {
        __syncthreads();                         // protect LDS reuse across buckets
        if (tid == 0) sbk = atomicAdd(wq, 1);
        __syncthreads();
        int b = sbk;
        if (b >= nbk) return;
        // bijective XCD swizzle (m204)
        int xcd = b & 7, idx = b >> 3;
        int bk  = (xcd < r8 ? xcd * (q8 + 1) : r8 * (q8 + 1) + (xcd - r8) * q8) + idx;
        int n0  = bk << BKSH;
        // phase A: strided seglen column read + wave-level scan
        int2 sl = (tid < nplace) ? seglen[(size_t)tid * MAXBK + bk] : make_int2(0, 0);
        ((int*)buf2)[tid] = sl.x;                // stash seg starts in buf2 scratch
        if (tid < BKN) {
            int node = n0 + tid;
            gdl[tid]  = (node < N) ? gdd[node] : make_float2(0.f, 0.f);
            hist[tid] = 0;
        }
        int v = sl.y;
        #pragma unroll
        for (int d = 1; d < 64; d <<= 1) {
            int t = __shfl_up(v, d, 64);
            if (lane >= d) v += t;
        }
        if (lane == 63) wtot[wid] = v;
        __syncthreads();
        int base = 0, c = 0;
        #pragma unroll
        for (int k = 0; k < 8; ++k) {
            base += (k < wid) ? wtot[k] : 0;
            c    += wtot[k];
        }
        sc[tid] = v + base;
        __syncthreads();
        if (c <= CAP) {
            // copy segments into stg, building hist on the fly
            for (int sp = (wid << 2) + qid; sp < nplace; sp += 32) {
                int inc  = sc[sp];
                int prev = (sp == 0) ? 0 : sc[sp - 1];
                int ll2  = inc - prev;
                int ss2  = ((int*)buf2)[sp];
                for (int k = l16; k < ll2; k += 16) {
                    int r = pairs[ss2 + k];
                    stg[prev + k] = r;
                    atomicAdd(&hist[r & (BKN - 1)], 1);
                }
            }
            __syncthreads();
            // node scan: single wave-0 shfl scan
            if (tid < BKN) {
                int hv = hist[tid];
                int v2 = hv;
                #pragma unroll
                for (int d = 1; d < BKN; d <<= 1) {
                    int t = __shfl_up(v2, d, 64);
                    if (tid >= d) v2 += t;
                }
                offl[tid + 1] = v2;
                cur[tid] = v2 - hv;
                if (tid == 0) offl[0] = 0;
            }
            __syncthreads();
            // permute into node-sorted buf2; ev folds int8 dequant scale
            for (int i = tid; i < c; i += 512) {
                int r  = stg[i];
                int lt = r & (BKN - 1);
                int s  = r >> BKSH;
                float4 bs = gss4[s];
                float2 ad = gdl[lt];
                float g  = fast_tanh(ad.x + bs.x + gb);
                float ev = g * ad.y * bs.y * bs.z;
                int p = atomicAdd(&cur[lt], 1);
                buf2[p] = make_int2(s, __float_as_int(ev));
            }
            __syncthreads();
            // quarter-wave int8 gather (proven R14 inner loop)
            for (int ln = wid; ln < BKN; ln += 8) {
                int node = n0 + ln;
                if (node >= N) break;
                int j   = offl[ln];
                int end = offl[ln + 1];
                float4 a0 = make_float4(0.f, 0.f, 0.f, 0.f);
                float4 a1 = a0, a2 = a0, a3 = a0;
                for (; j + 16 <= end; j += 16) {
                    int2 p0 = buf2[j + qid];
                    int2 p1 = buf2[j + qid + 4];
                    int2 p2 = buf2[j + qid + 8];
                    int2 p3 = buf2[j + qid + 12];
                    uint q0 = ((const uint*)(hq + (size_t)p0.x * DIM))[l16];
                    uint q1 = ((const uint*)(hq + (size_t)p1.x * DIM))[l16];
                    uint q2 = ((const uint*)(hq + (size_t)p2.x * DIM))[l16];
                    uint q3 = ((const uint*)(hq + (size_t)p3.x * DIM))[l16];
                    float e0 = __int_as_float(p0.y);
                    float e1 = __int_as_float(p1.y);
                    float e2 = __int_as_float(p2.y);
                    float e3 = __int_as_float(p3.y);
                    float4 h0 = i8x4_unpack(q0);
                    float4 h1 = i8x4_unpack(q1);
                    float4 h2 = i8x4_unpack(q2);
                    float4 h3 = i8x4_unpack(q3);
                    a0.x += h0.x * e0; a0.y += h0.y * e0; a0.z += h0.z * e0; a0.w += h0.w * e0;
                    a1.x += h1.x * e1; a1.y += h1.y * e1; a1.z += h1.z * e1; a1.w += h1.w * e1;
                    a2.x += h2.x * e2; a2.y += h2.y * e2; a2.z += h2.z * e2; a2.w += h2.w * e2;
                    a3.x += h3.x * e3; a3.y += h3.y * e3; a3.z += h3.z * e3; a3.w += h3.w * e3;
                }
                for (; j + 4 <= end; j += 4) {
                    int2 p = buf2[j + qid];
                    uint q = ((const uint*)(hq + (size_t)p.x * DIM))[l16];
                    float e = __int_as_float(p.y);
                    float4 hv = i8x4_unpack(q);
                    a0.x += hv.x * e; a0.y += hv.y * e; a0.z += hv.z * e; a0.w += hv.w * e;
                }
                int rem = end - j;
                if (rem > 0) {
                    int idx2 = j + (qid < rem ? qid : 0);
                    int2 p = buf2[idx2];
                    float e = (qid < rem) ? __int_as_float(p.y) : 0.f;
                    uint q = ((const uint*)(hq + (size_t)p.x * DIM))[l16];
                    float4 hv = i8x4_unpack(q);
                    a0.x += hv.x * e; a0.y += hv.y * e; a0.z += hv.z * e; a0.w += hv.w * e;
                }
                float4 t;
                t.x = a0.x + a1.x + a2.x + a3.x;
                t.y = a0.y + a1.y + a2.y + a3.y;
                t.z = a0.z + a1.z + a2.z + a3.z;
                t.w = a0.w + a1.w + a2.w + a3.w;
                t.x += __shfl_xor(t.x, 16, 64);  t.x += __shfl_xor(t.x, 32, 64);
                t.y += __shfl_xor(t.y, 16, 64);  t.y += __shfl_xor(t.y, 32, 64);
                t.z += __shfl_xor(t.z, 16, 64);  t.z += __shfl_xor(t.z, 32, 64);
                t.w += __shfl_xor(t.w, 16, 64);  t.w += __shfl_xor(t.w, 32, 64);
                if (qid == 0)
                    *(float4*)&z[(size_t)node * DIM + (l16 << 2)] = t;
            }
        } else {
            // adversarial-skew slow path: walk segments from global, filter (rare)
            for (int ln = wid; ln < BKN; ln += 8) {
                int node = n0 + ln;
                if (node >= N) break;
                float2 ad = gdl[ln];
                float acc = 0.f;
                for (int sp = 0; sp < nplace; ++sp) {
                    int2 sl2 = seglen[(size_t)sp * MAXBK + bk];
                    for (int i = 0; i < sl2.y; ++i) {
                        int r = pairs[sl2.x + i];
                        if ((r & (BKN - 1)) == ln) {
                            int s = r >> BKSH;
                            float4 bs = gss4[s];
                            float g  = fast_tanh(ad.x + bs.x + gb);
                            uint qw = ((const uint*)(hq + (size_t)s * DIM))[lane >> 2];
                            int qv = (int)(qw << ((3 - (lane & 3)) * 8)) >> 24;
                            acc += (float)qv * (g * ad.y * bs.y * bs.z);
                        }
                    }
                }
                z[(size_t)node * DIM + lane] = acc;
            }
        }
    }
}

// ---------- fallback: atomic scatter (uses f32 h) ----------
__global__ void fa_edge_scatter_atomic(const float* __restrict__ h,
                                       const float2* __restrict__ gdd,
                                       const float4* __restrict__ gss4,
                                       const int* __restrict__ esrc,
                                       const int* __restrict__ edst,
                                       const float* __restrict__ gate_b,
                                       float* __restrict__ z, int E) {
    int gid  = blockIdx.x * blockDim.x + threadIdx.x;
    int edge = gid >> 6;
    int lane = threadIdx.x & 63;
    if (edge >= E) return;
    int s = esrc[edge];
    int t = edst[edge];
    float2 ad = gdd[t];
    float4 bs = gss4[s];
    float g  = fast_tanh(ad.x + bs.x + gate_b[0]);
    float ev = g * ad.y * bs.y;
    atomicAdd(&z[(size_t)t * DIM + lane], h[(size_t)s * DIM + lane] * ev);
}

extern "C" void kernel_launch(void* const* d_in, const int* in_sizes, int n_in,
                              void* d_out, int out_size, void* d_ws, size_t ws_size,
                              hipStream_t stream) {
    const float* h      = (const float*)d_in[0];
    const float* dn     = (const float*)d_in[1];
    const float* gate_W = (const float*)d_in[2];
    const float* gate_b = (const float*)d_in[3];
    const int*   esrc   = (const int*)d_in[4];
    const int*   edst   = (const int*)d_in[5];
    float*       z      = (float*)d_out;

    int N = in_sizes[1];
    int E = in_sizes[4];
    int nbk    = (N + BKN - 1) >> BKSH;
    int nplace = (E + PCHUNK - 1) / PCHUNK;

    // workspace layout
    char* w = (char*)d_ws;
    float2* gdd  = (float2*)w;         w += (size_t)N * 8;
    float4* gss4 = (float4*)w;         w += (size_t)N * 16;
    w = (char*)(((uintptr_t)w + 63) & ~(uintptr_t)63);
    int2*  seglen = (int2*)w;          w += (size_t)MAXPB * MAXBK * 8;  // 6.55 MB
    int*  pairs  = (int*)w;            w += ((size_t)E + 64) * 4;
    int*  wq     = (int*)w;            w += 64;
    unsigned char* hq = (unsigned char*)w;
    w += (size_t)N * DIM;              // 6.4 MB int8 table
    size_t required = (size_t)(w - (char*)d_ws);
    size_t atomic_required = (size_t)N * 24;

    bool use_sort = (ws_size >= required) && (nbk <= MAXBK) && (nplace <= MAXPB);

    if (use_sort) {
        int gatesBlocks = (N + 63) / 64;         // 1024 thr = 64 nodes/block
        hipMemsetAsync(wq, 0, 4, stream);
        fa_place_gates<<<nplace + gatesBlocks, 1024, 0, stream>>>(
            h, gate_W, dn, gdd, gss4, hq, esrc, edst, seglen, pairs,
            E, N, nbk, nplace);
        int gblocks = nbk < 1024 ? nbk : 1024;
        fa_gather13<<<gblocks, 512, 0, stream>>>(hq, gdd, gss4, gate_b, seglen,
                                                 pairs, wq, z, N, nbk, nplace);
    } else if (ws_size >= atomic_required) {
        fa_node_gates<<<(N + 3) / 4, 256, 0, stream>>>(h, gate_W, dn, gdd, gss4, N);
        hipMemsetAsync(z, 0, (size_t)out_size * sizeof(float), stream);
        fa_edge_scatter_atomic<<<(E + 3) / 4, 256, 0, stream>>>(h, gdd, gss4, esrc,
                                                                edst, gate_b, z, E);
    }
}

// Round 21
// 104.337 us; speedup vs baseline: 1.2549x; 1.2549x over previous
//
#include <hip/hip_runtime.h>
#include <hip/hip_bf16.h>

#define DIM 64
#define BKN 64               // nodes per bucket
#define BKSH 6               // log2(BKN)
#define MAXBK 1600           // supports N <= 102400
#define PCHUNK 12288         // edges per place block (output window = 48 KB)
#define MAXPB 512            // max place blocks (E <= 6.29M)
#define CAP 2944             // gather LDS record capacity; mean ~2048, ~20 sigma

__device__ inline float fast_tanh(float x) {
    float e = __expf(2.0f * x);
    return 1.0f - 2.0f / (e + 1.0f);
}

__device__ inline float4 i8x4_unpack(uint q) {
    return make_float4((float)((int)(q << 24) >> 24),
                       (float)((int)(q << 16) >> 24),
                       (float)((int)(q <<  8) >> 24),
                       (float)((int)q >> 24));
}

// ---------- fused: place role (blocks [0,nplace)) + gates/quant role (rest) ----------
// seg table layout [blk][bk] (int2{start,len}): contiguous per-block writes.
__global__ __launch_bounds__(1024)
void fa_place_gates(const float* __restrict__ h,
                    const float* __restrict__ gate_W,
                    const float* __restrict__ dn,
                    float2* __restrict__ gdd,
                    float4* __restrict__ gss4,
                    unsigned char* __restrict__ hq,
                    const int* __restrict__ esrc, const int* __restrict__ edst,
                    int2* __restrict__ seglen,
                    int* __restrict__ pairs,
                    int E, int N, int nbk, int nplace) {
    __shared__ int stage[PCHUNK];                 // 48 KB staged records
    __shared__ int lh[2048];
    __shared__ int lex[2048];
    __shared__ int wtot[16];
    int tid = threadIdx.x;                        // 1024 threads
    if ((int)blockIdx.x < nplace) {
        int blk = blockIdx.x;
        int c0 = blk * PCHUNK;
        int c1 = min(E, c0 + PCHUNK);
        lh[tid] = 0; lh[tid + 1024] = 0;
        __syncthreads();
        // phase A: read edges once; stage record in LDS; histogram
        for (int i = c0 + tid; i < c1; i += 1024) {
            int t = edst[i];
            int s = esrc[i];
            stage[i - c0] = (s << BKSH) | (t & (BKN - 1));
            atomicAdd(&lh[t >> BKSH], 1);
        }
        __syncthreads();
        // phase B: wave-level exclusive scan over 2048 buckets (2 per thread)
        int lane = tid & 63, wv = tid >> 6;       // 16 waves
        int a0 = lh[2 * tid], a1 = lh[2 * tid + 1];
        int s = a0 + a1;
        int v = s;
        #pragma unroll
        for (int d = 1; d < 64; d <<= 1) {
            int t = __shfl_up(v, d, 64);
            if (lane >= d) v += t;
        }
        if (lane == 63) wtot[wv] = v;
        __syncthreads();
        int base = 0;
        #pragma unroll
        for (int k = 0; k < 16; ++k) base += (k < wv) ? wtot[k] : 0;
        int excl = v + base - s;
        lex[2 * tid] = excl;
        lex[2 * tid + 1] = excl + a0;
        __syncthreads();
        // segment table: contiguous per-block row [blk][bk]
        int2* row = seglen + (size_t)blk * MAXBK;
        for (int i = tid; i < nbk; i += 1024)
            row[i] = make_int2(c0 + lex[i], lh[i]);
        __syncthreads();
        // phase C: place staged records (edst re-read is L2-hot)
        for (int i = c0 + tid; i < c1; i += 1024) {
            int t = edst[i];
            int pos = c0 + atomicAdd(&lex[t >> BKSH], 1);
            pairs[pos] = stage[i - c0];
        }
    } else {
        // -------- gates + int8 quantization: 64 nodes/block, 4 nodes/wave --------
        int base_node = (blockIdx.x - nplace) * 64;
        int wv   = tid >> 6;
        int lane = tid & 63;
        int l16  = lane & 15;
        int node = base_node + (wv << 2) + (lane >> 4);
        if (node >= N) return;
        float4 x4 = ((const float4*)h)[(size_t)node * 16 + l16];
        float4 w0 = ((const float4*)gate_W)[l16];
        float4 w1 = ((const float4*)gate_W)[16 + l16];
        float a = x4.x * w0.x + x4.y * w0.y + x4.z * w0.z + x4.w * w0.w;
        float b = x4.x * w1.x + x4.y * w1.y + x4.z * w1.z + x4.w * w1.w;
        float m = fmaxf(fmaxf(fabsf(x4.x), fabsf(x4.y)),
                        fmaxf(fabsf(x4.z), fabsf(x4.w)));
        #pragma unroll
        for (int off = 1; off < 16; off <<= 1) {
            a += __shfl_xor(a, off, 16);
            b += __shfl_xor(b, off, 16);
            m = fmaxf(m, __shfl_xor(m, off, 16));
        }
        float inv = (m > 0.f) ? (127.0f / m) : 0.f;
        int q0 = __float2int_rn(x4.x * inv) & 0xff;
        int q1 = __float2int_rn(x4.y * inv) & 0xff;
        int q2 = __float2int_rn(x4.z * inv) & 0xff;
        int q3 = __float2int_rn(x4.w * inv) & 0xff;
        ((uint*)hq)[(size_t)node * 16 + l16] =
            (uint)q0 | ((uint)q1 << 8) | ((uint)q2 << 16) | ((uint)q3 << 24);
        if (l16 == 0) {
            float dv = dn[node];
            gdd[node]  = make_float2(a, dv);
            gss4[node] = make_float4(b, dv, m / 127.0f, 0.f);
        }
    }
}

// ---------- standalone gates (fallback path only) ----------
__global__ void fa_node_gates(const float* __restrict__ h,
                              const float* __restrict__ gate_W,
                              const float* __restrict__ dn,
                              float2* __restrict__ gdd,
                              float4* __restrict__ gss4,
                              int N) {
    int gid  = blockIdx.x * blockDim.x + threadIdx.x;
    int node = gid >> 6;
    int lane = threadIdx.x & 63;
    if (node >= N) return;
    float x = h[(size_t)node * DIM + lane];
    float a = x * gate_W[lane];
    float b = x * gate_W[DIM + lane];
    #pragma unroll
    for (int off = 32; off >= 1; off >>= 1) {
        a += __shfl_xor(a, off, 64);
        b += __shfl_xor(b, off, 64);
    }
    if (lane == 0) {
        float dv = dn[node];
        gdd[node]  = make_float2(a, dv);
        gss4[node] = make_float4(b, dv, 0.f, 0.f);
    }
}

// ---------- gather: strided seglen read -> wave-scan -> LDS sort -> quarter-wave int8 ----------
__global__ __launch_bounds__(512, 4)
void fa_gather12(const unsigned char* __restrict__ hq,
                 const float2* __restrict__ gdd, const float4* __restrict__ gss4,
                 const float* __restrict__ gate_b,
                 const int2* __restrict__ seglen,
                 const int* __restrict__ pairs,
                 float* __restrict__ z, int N, int nbk, int nplace) {
    __shared__ int  stg[CAP];                    // 11.5 KB raw records
    __shared__ int2 buf2[CAP];                   // 23 KB; first 2KB doubles as sstart scratch
    __shared__ int  sc[512];                     // segment-length inclusive scan
    __shared__ int  wtot[8];
    __shared__ float2 gdl[BKN];
    __shared__ int hist[BKN];
    __shared__ int cur[BKN];
    __shared__ int offl[BKN + 1];
    // bijective XCD swizzle (m204): consecutive bk -> same XCD
    int b   = blockIdx.x;
    int q8  = nbk >> 3, r8 = nbk & 7;
    int xcd = b & 7, idx = b >> 3;
    int bk  = (xcd < r8 ? xcd * (q8 + 1) : r8 * (q8 + 1) + (xcd - r8) * q8) + idx;
    int tid = threadIdx.x;                       // 512 threads = 8 waves
    int n0  = bk << BKSH;
    int wid  = tid >> 6;
    int lane = tid & 63;
    float gb = gate_b[0];
    // phase A: strided seglen column read + wave-level scan (2 barriers)
    int2 sl = (tid < nplace) ? seglen[(size_t)tid * MAXBK + bk] : make_int2(0, 0);
    ((int*)buf2)[tid] = sl.x;                    // stash seg starts in buf2 scratch
    int ll = sl.y;
    if (tid < BKN) {
        int node = n0 + tid;
        gdl[tid]  = (node < N) ? gdd[node] : make_float2(0.f, 0.f);
        hist[tid] = 0;
    }
    int v = ll;
    #pragma unroll
    for (int d = 1; d < 64; d <<= 1) {
        int t = __shfl_up(v, d, 64);
        if (lane >= d) v += t;
    }
    if (lane == 63) wtot[wid] = v;
    __syncthreads();
    int base = 0, c = 0;
    #pragma unroll
    for (int k = 0; k < 8; ++k) {
        base += (k < wid) ? wtot[k] : 0;
        c    += wtot[k];
    }
    sc[tid] = v + base;
    __syncthreads();
    if (c <= CAP) {
        // copy segments into stg, building hist on the fly
        int qid = lane >> 4;
        int l16 = lane & 15;
        for (int sp = (wid << 2) + qid; sp < nplace; sp += 32) {
            int inc  = sc[sp];
            int prev = (sp == 0) ? 0 : sc[sp - 1];
            int ll2  = inc - prev;
            int ss2  = ((int*)buf2)[sp];
            for (int k = l16; k < ll2; k += 16) {
                int r = pairs[ss2 + k];
                stg[prev + k] = r;
                atomicAdd(&hist[r & (BKN - 1)], 1);
            }
        }
        __syncthreads();
        // node scan: single wave-0 shfl scan
        if (tid < BKN) {
            int hv = hist[tid];
            int v2 = hv;
            #pragma unroll
            for (int d = 1; d < BKN; d <<= 1) {
                int t = __shfl_up(v2, d, 64);
                if (tid >= d) v2 += t;
            }
            offl[tid + 1] = v2;
            cur[tid] = v2 - hv;
            if (tid == 0) offl[0] = 0;
        }
        __syncthreads();
        // permute into node-sorted buf2 (overwrites scratch; copy already done)
        for (int i = tid; i < c; i += 512) {
            int r  = stg[i];
            int lt = r & (BKN - 1);
            int s  = r >> BKSH;
            float4 bs = gss4[s];
            float2 ad = gdl[lt];
            float g  = fast_tanh(ad.x + bs.x + gb);
            float ev = g * ad.y * bs.y * bs.z;
            int p = atomicAdd(&cur[lt], 1);
            buf2[p] = make_int2(s, __float_as_int(ev));
        }
        __syncthreads();
        // quarter-wave int8 gather (proven R14 inner loop)
        for (int ln = wid; ln < BKN; ln += 8) {
            int node = n0 + ln;
            if (node >= N) break;
            int j   = offl[ln];
            int end = offl[ln + 1];
            float4 a0 = make_float4(0.f, 0.f, 0.f, 0.f);
            float4 a1 = a0, a2 = a0, a3 = a0;
            for (; j + 16 <= end; j += 16) {
                int2 p0 = buf2[j + qid];
                int2 p1 = buf2[j + qid + 4];
                int2 p2 = buf2[j + qid + 8];
                int2 p3 = buf2[j + qid + 12];
                uint q0 = ((const uint*)(hq + (size_t)p0.x * DIM))[l16];
                uint q1 = ((const uint*)(hq + (size_t)p1.x * DIM))[l16];
                uint q2 = ((const uint*)(hq + (size_t)p2.x * DIM))[l16];
                uint q3 = ((const uint*)(hq + (size_t)p3.x * DIM))[l16];
                float e0 = __int_as_float(p0.y);
                float e1 = __int_as_float(p1.y);
                float e2 = __int_as_float(p2.y);
                float e3 = __int_as_float(p3.y);
                float4 h0 = i8x4_unpack(q0);
                float4 h1 = i8x4_unpack(q1);
                float4 h2 = i8x4_unpack(q2);
                float4 h3 = i8x4_unpack(q3);
                a0.x += h0.x * e0; a0.y += h0.y * e0; a0.z += h0.z * e0; a0.w += h0.w * e0;
                a1.x += h1.x * e1; a1.y += h1.y * e1; a1.z += h1.z * e1; a1.w += h1.w * e1;
                a2.x += h2.x * e2; a2.y += h2.y * e2; a2.z += h2.z * e2; a2.w += h2.w * e2;
                a3.x += h3.x * e3; a3.y += h3.y * e3; a3.z += h3.z * e3; a3.w += h3.w * e3;
            }
            for (; j + 4 <= end; j += 4) {
                int2 p = buf2[j + qid];
                uint q = ((const uint*)(hq + (size_t)p.x * DIM))[l16];
                float e = __int_as_float(p.y);
                float4 hv = i8x4_unpack(q);
                a0.x += hv.x * e; a0.y += hv.y * e; a0.z += hv.z * e; a0.w += hv.w * e;
            }
            int rem = end - j;
            if (rem > 0) {
                int idx2 = j + (qid < rem ? qid : 0);
                int2 p = buf2[idx2];
                float e = (qid < rem) ? __int_as_float(p.y) : 0.f;
                uint q = ((const uint*)(hq + (size_t)p.x * DIM))[l16];
                float4 hv = i8x4_unpack(q);
                a0.x += hv.x * e; a0.y += hv.y * e; a0.z += hv.z * e; a0.w += hv.w * e;
            }
            float4 t;
            t.x = a0.x + a1.x + a2.x + a3.x;
            t.y = a0.y + a1.y + a2.y + a3.y;
            t.z = a0.z + a1.z + a2.z + a3.z;
            t.w = a0.w + a1.w + a2.w + a3.w;
            t.x += __shfl_xor(t.x, 16, 64);  t.x += __shfl_xor(t.x, 32, 64);
            t.y += __shfl_xor(t.y, 16, 64);  t.y += __shfl_xor(t.y, 32, 64);
            t.z += __shfl_xor(t.z, 16, 64);  t.z += __shfl_xor(t.z, 32, 64);
            t.w += __shfl_xor(t.w, 16, 64);  t.w += __shfl_xor(t.w, 32, 64);
            if (qid == 0)
                *(float4*)&z[(size_t)node * DIM + (l16 << 2)] = t;
        }
    } else {
        // adversarial-skew slow path: walk segments from global, filter (rare)
        for (int ln = wid; ln < BKN; ln += 8) {
            int node = n0 + ln;
            if (node >= N) break;
            float2 ad = gdl[ln];
            float acc = 0.f;
            for (int sp = 0; sp < nplace; ++sp) {
                int2 sl2 = seglen[(size_t)sp * MAXBK + bk];
                for (int i = 0; i < sl2.y; ++i) {
                    int r = pairs[sl2.x + i];
                    if ((r & (BKN - 1)) == ln) {
                        int s = r >> BKSH;
                        float4 bs = gss4[s];
                        float g  = fast_tanh(ad.x + bs.x + gb);
                        uint qw = ((const uint*)(hq + (size_t)s * DIM))[lane >> 2];
                        int qv = (int)(qw << ((3 - (lane & 3)) * 8)) >> 24;
                        acc += (float)qv * (g * ad.y * bs.y * bs.z);
                    }
                }
            }
            z[(size_t)node * DIM + lane] = acc;
        }
    }
}

// ---------- fallback: atomic scatter (uses f32 h) ----------
__global__ void fa_edge_scatter_atomic(const float* __restrict__ h,
                                       const float2* __restrict__ gdd,
                                       const float4* __restrict__ gss4,
                                       const int* __restrict__ esrc,
                                       const int* __restrict__ edst,
                                       const float* __restrict__ gate_b,
                                       float* __restrict__ z, int E) {
    int gid  = blockIdx.x * blockDim.x + threadIdx.x;
    int edge = gid >> 6;
    int lane = threadIdx.x & 63;
    if (edge >= E) return;
    int s = esrc[edge];
    int t = edst[edge];
    float2 ad = gdd[t];
    float4 bs = gss4[s];
    float g  = fast_tanh(ad.x + bs.x + gate_b[0]);
    float ev = g * ad.y * bs.y;
    atomicAdd(&z[(size_t)t * DIM + lane], h[(size_t)s * DIM + lane] * ev);
}

extern "C" void kernel_launch(void* const* d_in, const int* in_sizes, int n_in,
                              void* d_out, int out_size, void* d_ws, size_t ws_size,
                              hipStream_t stream) {
    const float* h      = (const float*)d_in[0];
    const float* dn     = (const float*)d_in[1];
    const float* gate_W = (const float*)d_in[2];
    const float* gate_b = (const float*)d_in[3];
    const int*   esrc   = (const int*)d_in[4];
    const int*   edst   = (const int*)d_in[5];
    float*       z      = (float*)d_out;

    int N = in_sizes[1];
    int E = in_sizes[4];
    int nbk    = (N + BKN - 1) >> BKSH;
    int nplace = (E + PCHUNK - 1) / PCHUNK;

    // workspace layout
    char* w = (char*)d_ws;
    float2* gdd  = (float2*)w;         w += (size_t)N * 8;
    float4* gss4 = (float4*)w;         w += (size_t)N * 16;
    w = (char*)(((uintptr_t)w + 63) & ~(uintptr_t)63);
    int2*  seglen = (int2*)w;          w += (size_t)MAXPB * MAXBK * 8;  // 6.55 MB
    int*  pairs  = (int*)w;            w += ((size_t)E + 64) * 4;
    unsigned char* hq = (unsigned char*)w;
    w += (size_t)N * DIM;              // 6.4 MB int8 table
    size_t required = (size_t)(w - (char*)d_ws);
    size_t atomic_required = (size_t)N * 24;

    bool use_sort = (ws_size >= required) && (nbk <= MAXBK) && (nplace <= MAXPB);

    if (use_sort) {
        int gatesBlocks = (N + 63) / 64;         // 1024 thr = 64 nodes/block
        fa_place_gates<<<nplace + gatesBlocks, 1024, 0, stream>>>(
            h, gate_W, dn, gdd, gss4, hq, esrc, edst, seglen, pairs,
            E, N, nbk, nplace);
        fa_gather12<<<nbk, 512, 0, stream>>>(hq, gdd, gss4, gate_b, seglen,
                                             pairs, z, N, nbk, nplace);
    } else if (ws_size >= atomic_required) {
        fa_node_gates<<<(N + 3) / 4, 256, 0, stream>>>(h, gate_W, dn, gdd, gss4, N);
        hipMemsetAsync(z, 0, (size_t)out_size * sizeof(float), stream);
        fa_edge_scatter_atomic<<<(E + 3) / 4, 256, 0, stream>>>(h, gdd, gss4, esrc,
                                                                edst, gate_b, z, E);
    }
}